// Round 1
// baseline (274.606 us; speedup 1.0000x reference)
//
#include <hip/hip_runtime.h>
#include <hip/hip_bf16.h>
#include <math.h>

typedef __bf16 bf16x8 __attribute__((ext_vector_type(8)));
typedef __bf16 bf16x4 __attribute__((ext_vector_type(4)));
typedef float  f32x4  __attribute__((ext_vector_type(4)));

#define QBLK  64
#define KVBLK 64
#define HD    64
#define LDK   72   // pad: 144B row stride -> 2 lanes/bank (free)
#define LDV   72
#define LDP   72

__global__ __launch_bounds__(256)
void fattn_fwd(const float* __restrict__ Q, const float* __restrict__ K,
               const float* __restrict__ V, const int* __restrict__ causal_p,
               float* __restrict__ O, int B, int N, int H) {
  __shared__ alignas(16) __bf16 Kl[KVBLK][LDK];   // K[kv][d]
  __shared__ alignas(16) __bf16 Vl[HD][LDV];      // V^T[d][kv]
  __shared__ alignas(16) __bf16 Pl[QBLK][LDP];    // P[q][kv], per-wave rows

  const int tid  = threadIdx.x;
  const int wave = tid >> 6;
  const int lane = tid & 63;
  const int lo   = lane & 15;
  const int hi   = lane >> 4;

  const int q0 = blockIdx.x * QBLK;
  const int bh = blockIdx.y;
  const int bb = bh / H;
  const int hh = bh - bb * H;

  const int causal = causal_p[0];
  const int sN = H * HD;  // elems between consecutive n for fixed (b,h)

  const float* Qb = Q + (long)bb * N * sN + hh * HD;
  const float* Kb = K + (long)bb * N * sN + hh * HD;
  const float* Vb = V + (long)bb * N * sN + hh * HD;
  float*       Ob = O + (long)bb * N * sN + hh * HD;

  // ---- Q fragments in registers, scaled by 1/sqrt(d)*log2(e) (exp2 softmax) ----
  const float qscale = 0.125f * 1.44269504088896340736f;
  bf16x8 aq[2];
  {
    const float* qp = Qb + (long)(q0 + wave * 16 + lo) * sN;
#pragma unroll
    for (int c = 0; c < 2; ++c) {
      f32x4 x0 = *(const f32x4*)(qp + c * 32 + hi * 8);
      f32x4 x1 = *(const f32x4*)(qp + c * 32 + hi * 8 + 4);
      bf16x8 a;
#pragma unroll
      for (int j = 0; j < 4; ++j) {
        a[j]     = (__bf16)(x0[j] * qscale);
        a[j + 4] = (__bf16)(x1[j] * qscale);
      }
      aq[c] = a;
    }
  }

  f32x4 acc[4];
#pragma unroll
  for (int i = 0; i < 4; ++i) acc[i] = (f32x4){0.f, 0.f, 0.f, 0.f};
  float m_run[4], l_run[4];
#pragma unroll
  for (int r = 0; r < 4; ++r) { m_run[r] = -INFINITY; l_run[r] = 0.f; }

  const int ntiles = causal ? (q0 / KVBLK + 1) : (N / KVBLK);

  for (int t = 0; t < ntiles; ++t) {
    const int k0 = t * KVBLK;
    __syncthreads();  // prior PV reads of Kl/Vl done before overwrite
    // ---- stage K (row-major bf16) and V^T (bf16) ----
#pragma unroll
    for (int i = 0; i < 4; ++i) {
      const int flat = tid + i * 256;       // float4 index, 1024 total
      const int r    = flat >> 4;           // kv row 0..63
      const int c4   = (flat & 15) * 4;     // d offset
      const long goff = (long)(k0 + r) * sN + c4;
      f32x4 kx = *(const f32x4*)(Kb + goff);
      bf16x4 kb;
#pragma unroll
      for (int j = 0; j < 4; ++j) kb[j] = (__bf16)kx[j];
      *(bf16x4*)&Kl[r][c4] = kb;
      f32x4 vx = *(const f32x4*)(Vb + goff);
#pragma unroll
      for (int j = 0; j < 4; ++j) Vl[c4 + j][r] = (__bf16)vx[j];
    }
    __syncthreads();

    // ---- S = (scaled Q) K^T ; s[nt][r] = S[q=hi*4+r][kv=nt*16+lo] ----
    f32x4 s[4];
#pragma unroll
    for (int nt = 0; nt < 4; ++nt) s[nt] = (f32x4){0.f, 0.f, 0.f, 0.f};
#pragma unroll
    for (int c = 0; c < 2; ++c) {
#pragma unroll
      for (int nt = 0; nt < 4; ++nt) {
        bf16x8 b = *(const bf16x8*)&Kl[nt * 16 + lo][c * 32 + hi * 8];
        s[nt] = __builtin_amdgcn_mfma_f32_16x16x32_bf16(aq[c], b, s[nt], 0, 0, 0);
      }
    }

    // ---- causal mask: only the diagonal tile needs it ----
    if (causal && t == ntiles - 1) {
#pragma unroll
      for (int nt = 0; nt < 4; ++nt) {
        const int kvg = k0 + nt * 16 + lo;
#pragma unroll
        for (int r = 0; r < 4; ++r) {
          const int qg = q0 + wave * 16 + hi * 4 + r;
          if (kvg > qg) s[nt][r] = -INFINITY;
        }
      }
    }

    // ---- online softmax (exp2 domain), 16-lane butterfly per q-row ----
#pragma unroll
    for (int r = 0; r < 4; ++r) {
      float mx = fmaxf(fmaxf(s[0][r], s[1][r]), fmaxf(s[2][r], s[3][r]));
      mx = fmaxf(mx, __shfl_xor(mx, 1));
      mx = fmaxf(mx, __shfl_xor(mx, 2));
      mx = fmaxf(mx, __shfl_xor(mx, 4));
      mx = fmaxf(mx, __shfl_xor(mx, 8));
      const float mnew = fmaxf(m_run[r], mx);
      const float fac  = exp2f(m_run[r] - mnew);  // first tile: exp2(-inf)=0
      float ps = 0.f;
#pragma unroll
      for (int nt = 0; nt < 4; ++nt) {
        const float p = exp2f(s[nt][r] - mnew);   // masked -inf -> 0
        s[nt][r] = p;
        ps += p;
      }
      ps += __shfl_xor(ps, 1);
      ps += __shfl_xor(ps, 2);
      ps += __shfl_xor(ps, 4);
      ps += __shfl_xor(ps, 8);
      l_run[r] = l_run[r] * fac + ps;
      m_run[r] = mnew;
#pragma unroll
      for (int nt = 0; nt < 4; ++nt) acc[nt][r] *= fac;
    }

    // ---- P -> LDS (bf16) to reach PV A-fragment layout ----
#pragma unroll
    for (int nt = 0; nt < 4; ++nt)
#pragma unroll
      for (int r = 0; r < 4; ++r)
        Pl[wave * 16 + hi * 4 + r][nt * 16 + lo] = (__bf16)s[nt][r];
    __syncthreads();  // drains lgkm; within-wave write->read ordering

    // ---- O += P V ----
#pragma unroll
    for (int c = 0; c < 2; ++c) {
      bf16x8 pa = *(const bf16x8*)&Pl[wave * 16 + lo][c * 32 + hi * 8];
#pragma unroll
      for (int nt = 0; nt < 4; ++nt) {
        bf16x8 vb = *(const bf16x8*)&Vl[nt * 16 + lo][c * 32 + hi * 8];
        acc[nt] = __builtin_amdgcn_mfma_f32_16x16x32_bf16(pa, vb, acc[nt], 0, 0, 0);
      }
    }
  }

  // ---- epilogue: O = acc / l ----
  {
    const int qrow = q0 + wave * 16 + hi * 4;
#pragma unroll
    for (int nt = 0; nt < 4; ++nt) {
#pragma unroll
      for (int r = 0; r < 4; ++r) {
        Ob[(long)(qrow + r) * sN + nt * 16 + lo] = acc[nt][r] / l_run[r];
      }
    }
  }
}

extern "C" void kernel_launch(void* const* d_in, const int* in_sizes, int n_in,
                              void* d_out, int out_size, void* d_ws, size_t ws_size,
                              hipStream_t stream) {
  const float* q = (const float*)d_in[0];
  const float* k = (const float*)d_in[1];
  const float* v = (const float*)d_in[2];
  const int* causal = (const int*)d_in[3];
  float* out = (float*)d_out;
  const int B = 2, N = 2048, H = 16;
  dim3 grid(N / QBLK, B * H);
  fattn_fwd<<<grid, dim3(256), 0, stream>>>(q, k, v, causal, out, B, N, H);
}

// Round 2
// 167.168 us; speedup vs baseline: 1.6427x; 1.6427x over previous
//
#include <hip/hip_runtime.h>
#include <hip/hip_bf16.h>
#include <math.h>

typedef __bf16 bf16x8 __attribute__((ext_vector_type(8)));
typedef __bf16 bf16x4 __attribute__((ext_vector_type(4)));
typedef float  f32x4  __attribute__((ext_vector_type(4)));

#define KVBLK 64
#define HD    64
#define LDK   72   // 144B stride: b128 reads 16B-aligned, ~2-way banks
#define LDV   68   // 136B stride: b64 ops 8B-aligned, rows step 2 banks
#define LDP   72
#define NQT   32   // N / 64

__global__ __launch_bounds__(256, 2)
void fattn_fwd(const float* __restrict__ Q, const float* __restrict__ K,
               const float* __restrict__ V, const int* __restrict__ causal_p,
               float* __restrict__ O, int B, int N, int H) {
  __shared__ alignas(16) __bf16 Kl[KVBLK][LDK];   // K[kv][d]
  __shared__ alignas(16) __bf16 Vl[HD][LDV];      // V^T[d][kv]
  __shared__ alignas(16) __bf16 Pl[64][LDP];      // P[q][kv], wave-private rows

  const int tid  = threadIdx.x;
  const int wave = tid >> 6;
  const int lane = tid & 63;
  const int lo   = lane & 15;
  const int hi   = lane >> 4;

  // paired q-tiles: xA in [0,15], xB = 31-xA  -> uniform 33 tile-units/block
  const int xA = blockIdx.x;
  const int xB = NQT - 1 - xA;
  const int bh = blockIdx.y;
  const int bb = bh / H;
  const int hh = bh - bb * H;

  const int causal = causal_p[0];
  const int sN = H * HD;

  const float* Qb = Q + (long)bb * N * sN + hh * HD;
  const float* Kb = K + (long)bb * N * sN + hh * HD;
  const float* Vb = V + (long)bb * N * sN + hh * HD;
  float*       Ob = O + (long)bb * N * sN + hh * HD;

  const int tmaxA = causal ? xA : (NQT - 1);
  const int tmaxB = causal ? xB : (NQT - 1);

  // ---- Q fragments for both tiles, scaled by 1/sqrt(d)*log2(e) ----
  const float qscale = 0.125f * 1.44269504088896340736f;
  bf16x8 aq[2][2];
#pragma unroll
  for (int qi = 0; qi < 2; ++qi) {
    const int q0q = ((qi == 0) ? xA : xB) * 64;
    const float* qp = Qb + (long)(q0q + wave * 16 + lo) * sN;
#pragma unroll
    for (int c = 0; c < 2; ++c) {
      f32x4 x0 = *(const f32x4*)(qp + c * 32 + hi * 8);
      f32x4 x1 = *(const f32x4*)(qp + c * 32 + hi * 8 + 4);
      bf16x8 a;
#pragma unroll
      for (int j = 0; j < 4; ++j) {
        a[j]     = (__bf16)(x0[j] * qscale);
        a[j + 4] = (__bf16)(x1[j] * qscale);
      }
      aq[qi][c] = a;
    }
  }

  f32x4 acc[2][4];
  float m_run[2][4], l_run[2][4];
#pragma unroll
  for (int qi = 0; qi < 2; ++qi)
#pragma unroll
    for (int i = 0; i < 4; ++i) {
      acc[qi][i] = (f32x4){0.f, 0.f, 0.f, 0.f};
      m_run[qi][i] = -INFINITY;
      l_run[qi][i] = 0.f;
    }

  // ---- staging helpers: global -> regs (issue), regs -> LDS (write) ----
  f32x4 kreg[4], vreg[4];
  auto issue = [&](int tt) {
    const int k0 = tt * KVBLK;
#pragma unroll
    for (int i = 0; i < 4; ++i) {
      const int flat = tid + i * 256;
      const int r = flat >> 4, c4 = (flat & 15) * 4;
      kreg[i] = *(const f32x4*)(Kb + (long)(k0 + r) * sN + c4);
    }
    // V: lane owns 4x4 (kv x d) block -> free in-register transpose
    const float* vrow = Vb + (long)(k0 + wave * 16 + hi * 4) * sN + lo * 4;
#pragma unroll
    for (int q = 0; q < 4; ++q) vreg[q] = *(const f32x4*)(vrow + (long)q * sN);
  };
  auto wr = [&]() {
#pragma unroll
    for (int i = 0; i < 4; ++i) {
      const int flat = tid + i * 256;
      const int r = flat >> 4, c4 = (flat & 15) * 4;
      bf16x4 kb;
#pragma unroll
      for (int j = 0; j < 4; ++j) kb[j] = (__bf16)kreg[i][j];
      *(bf16x4*)&Kl[r][c4] = kb;
    }
#pragma unroll
    for (int j = 0; j < 4; ++j) {
      bf16x4 vv;
#pragma unroll
      for (int q = 0; q < 4; ++q) vv[q] = (__bf16)vreg[q][j];
      *(bf16x4*)&Vl[lo * 4 + j][wave * 16 + hi * 4] = vv;
    }
  };

  // prologue: stage tile 0
  issue(0);
  wr();
  __syncthreads();

  for (int t = 0; t <= tmaxB; ++t) {
    const bool pf = (t < tmaxB);
    if (pf) issue(t + 1);  // HBM latency hides under compute below
    const int k0 = t * KVBLK;

#pragma unroll
    for (int qi = 0; qi < 2; ++qi) {
      if (qi == 0 && t > tmaxA) continue;
      const int qt  = (qi == 0) ? xA : xB;
      const int q0q = qt * 64;

      // ---- S = (scaled Q) K^T ----
      f32x4 s[4];
#pragma unroll
      for (int nt = 0; nt < 4; ++nt) s[nt] = (f32x4){0.f, 0.f, 0.f, 0.f};
#pragma unroll
      for (int c = 0; c < 2; ++c) {
#pragma unroll
        for (int nt = 0; nt < 4; ++nt) {
          bf16x8 b = *(const bf16x8*)&Kl[nt * 16 + lo][c * 32 + hi * 8];
          s[nt] = __builtin_amdgcn_mfma_f32_16x16x32_bf16(aq[qi][c], b, s[nt], 0, 0, 0);
        }
      }

      // ---- causal mask: only the diagonal tile ----
      if (causal && t == qt) {
#pragma unroll
        for (int nt = 0; nt < 4; ++nt) {
          const int kvg = k0 + nt * 16 + lo;
#pragma unroll
          for (int r = 0; r < 4; ++r) {
            const int qg = q0q + wave * 16 + hi * 4 + r;
            if (kvg > qg) s[nt][r] = -INFINITY;
          }
        }
      }

      // ---- online softmax (exp2 domain) ----
#pragma unroll
      for (int r = 0; r < 4; ++r) {
        float mx = fmaxf(fmaxf(s[0][r], s[1][r]), fmaxf(s[2][r], s[3][r]));
        mx = fmaxf(mx, __shfl_xor(mx, 1));
        mx = fmaxf(mx, __shfl_xor(mx, 2));
        mx = fmaxf(mx, __shfl_xor(mx, 4));
        mx = fmaxf(mx, __shfl_xor(mx, 8));
        const float mnew = fmaxf(m_run[qi][r], mx);
        const float fac  = exp2f(m_run[qi][r] - mnew);
        float ps = 0.f;
#pragma unroll
        for (int nt = 0; nt < 4; ++nt) {
          const float p = exp2f(s[nt][r] - mnew);
          s[nt][r] = p;
          ps += p;
        }
        ps += __shfl_xor(ps, 1);
        ps += __shfl_xor(ps, 2);
        ps += __shfl_xor(ps, 4);
        ps += __shfl_xor(ps, 8);
        l_run[qi][r] = l_run[qi][r] * fac + ps;
        m_run[qi][r] = mnew;
#pragma unroll
        for (int nt = 0; nt < 4; ++nt) acc[qi][nt][r] *= fac;
      }

      // ---- P -> LDS (wave-private rows; wave-local ordering only) ----
      asm volatile("s_waitcnt lgkmcnt(0)" ::: "memory");
#pragma unroll
      for (int nt = 0; nt < 4; ++nt)
#pragma unroll
        for (int r = 0; r < 4; ++r)
          Pl[wave * 16 + hi * 4 + r][nt * 16 + lo] = (__bf16)s[nt][r];
      asm volatile("s_waitcnt lgkmcnt(0)" ::: "memory");

      // ---- O += P V ----
#pragma unroll
      for (int c = 0; c < 2; ++c) {
        bf16x8 pa = *(const bf16x8*)&Pl[wave * 16 + lo][c * 32 + hi * 8];
#pragma unroll
        for (int nt = 0; nt < 4; ++nt) {
          const __bf16* vp = &Vl[nt * 16 + lo][c * 32 + hi * 8];
          bf16x4 v0 = *(const bf16x4*)vp;
          bf16x4 v1 = *(const bf16x4*)(vp + 4);
          bf16x8 vb;
#pragma unroll
          for (int j = 0; j < 4; ++j) { vb[j] = v0[j]; vb[j + 4] = v1[j]; }
          acc[qi][nt] = __builtin_amdgcn_mfma_f32_16x16x32_bf16(pa, vb, acc[qi][nt], 0, 0, 0);
        }
      }
    }

    __syncthreads();   // all waves done reading Kl/Vl tile t
    if (pf) wr();      // regs -> LDS for tile t+1
    __syncthreads();   // staging visible
  }

  // ---- epilogue ----
#pragma unroll
  for (int qi = 0; qi < 2; ++qi) {
    const int q0q = ((qi == 0) ? xA : xB) * 64;
    const int qrow = q0q + wave * 16 + hi * 4;
#pragma unroll
    for (int nt = 0; nt < 4; ++nt) {
#pragma unroll
      for (int r = 0; r < 4; ++r) {
        Ob[(long)(qrow + r) * sN + nt * 16 + lo] = acc[qi][nt][r] / l_run[qi][r];
      }
    }
  }
}

extern "C" void kernel_launch(void* const* d_in, const int* in_sizes, int n_in,
                              void* d_out, int out_size, void* d_ws, size_t ws_size,
                              hipStream_t stream) {
  const float* q = (const float*)d_in[0];
  const float* k = (const float*)d_in[1];
  const float* v = (const float*)d_in[2];
  const int* causal = (const int*)d_in[3];
  float* out = (float*)d_out;
  const int B = 2, N = 2048, H = 16;
  dim3 grid(NQT / 2, B * H);
  fattn_fwd<<<grid, dim3(256), 0, stream>>>(q, k, v, causal, out, B, N, H);
}